// Round 8
// baseline (6248.505 us; speedup 1.0000x reference)
//
#include <hip/hip_runtime.h>
#include <hip/hip_fp16.h>
#include <math.h>

#define B_  64
#define T_  800
#define U_  64
#define V_  60
#define C_  512
#define K_  10
#define KX  576   // padded hx: [0..3]=x(3)+pad, [4..63]=w(60), [64..575]=h(512)
#define NWG 256
#define NTH 1024  // 16 waves: (kq = w&7) x (colhalf = w>>3); 1 WG/CU
#define KQ  8     // k-split for gates GEMM
#define KSL 72    // KX / KQ
#define NB  4     // batches per group
#define GRPWG 16  // WGs per group

typedef unsigned long long ull;

// ws: ull hpair[2][B][C] (h value lo32, tag hi32) = 512KB, memset each launch
__device__ __forceinline__ float sigm(float v)  { return 1.f/(1.f+__expf(-v)); }
__device__ __forceinline__ float tanhx(float v) { return 1.f - 2.f/(__expf(2.f*v)+1.f); }

__global__ __launch_bounds__(NTH, 4)   // 4 waves/EU min => VGPR cap 128, 1 WG/CU
void lstm_attn_persistent(
    const float* __restrict__ x,         // [B,T,3]
    const float* __restrict__ onehots,   // [B,U,V]
    const float* __restrict__ text_lens, // [B,1]
    const float* __restrict__ w_old,     // [B,V]
    const float* __restrict__ kappa_old, // [B,K]
    const float* __restrict__ prev_h,    // [B,C]
    const float* __restrict__ prev_c,    // [B,C]
    const float* __restrict__ W_ih,      // [4C, 63]
    const float* __restrict__ W_hh,      // [4C, C]
    const float* __restrict__ b_ih,      // [4C]
    const float* __restrict__ b_hh,      // [4C]
    const float* __restrict__ win_W,     // [30, C]
    const float* __restrict__ win_b,     // [30]
    ull* __restrict__ hpair,
    float* __restrict__ out)
{
  // out layout (flat, return order)
  const long OUT_WS  = 0;
  const long OUT_HS  = (long)B_*T_*V_;
  const long OUT_H   = OUT_HS + (long)B_*T_*C_;
  const long OUT_C   = OUT_H  + (long)B_*C_;
  const long OUT_W   = OUT_C  + (long)B_*C_;
  const long OUT_KAP = OUT_W  + (long)B_*V_;
  const long OUT_PHI = OUT_KAP+ (long)B_*K_;

  const int tid  = threadIdx.x;
  const int wav  = tid >> 6;        // 0..15
  const int kq   = wav & 7;         // gates k-slice
  const int sA   = wav >> 3;        // gates col-half (64 cols each)
  const int lane = tid & 63;
  const int bid  = blockIdx.x;
  const int grp  = bid & 15;        // group id (4 batches)
  const int gblk = bid >> 4;        // 0..15: 128-gate-col block
  const int b0   = grp * NB;

  __shared__ __align__(16) float hx[NB][KX];          // per-b extended input vector
  __shared__ __align__(16) float part[KQ][NB][2][68]; // gates: [kq][bb][sA][lane]; win: [wav>>1][bb][wav&1][lane]
  __shared__ float p_lds[NB][32];
  __shared__ float kap_lds[NB][12];
  __shared__ float scale_lds[NB];
  __shared__ int   ids_lds[NB][64];

  // ---- persistent registers ----
  // permuted gate col gp = ch*4 + gate; this thread owns ONE col, f16 k-packed
  __half2 Wh2[KSL/2];               // 36 regs: k = kq*72 + 2i, 2i+1
  float bias1;
  {
    int gp   = gblk*128 + sA*64 + lane;
    int gate = gp & 3;
    int ch   = gp >> 2;
    int row  = gate*C_ + ch;
    #pragma unroll
    for (int i = 0; i < KSL/2; ++i) {
      float wv[2];
      #pragma unroll
      for (int s = 0; s < 2; ++s) {
        int k = kq*KSL + 2*i + s;
        float v;
        if      (k < 3)  v = W_ih[row*63 + k];
        else if (k == 3) v = 0.f;
        else if (k < 64) v = W_ih[row*63 + (k-1)];
        else             v = W_hh[row*C_ + (k-64)];
        wv[s] = v;
      }
      Wh2[i] = __floats2half2_rn(wv[0], wv[1]);
    }
    bias1 = b_ih[row] + b_hh[row];
  }

  // window projection (f32): 16 waves x 32 ch; lanes 0..59 -> (j=lane%30, half)
  const int wj = lane % 30;
  const int wh = (lane < 60) ? (lane / 30) : 0;
  float winreg[16];
  #pragma unroll
  for (int i = 0; i < 16; ++i)
    winreg[i] = win_W[wj*C_ + wav*32 + wh*16 + i];

  // LSTM cell state: tid<128 owns (bb = tid>>5, ch = gblk*32 + (tid&31))
  const int ub    = tid >> 5;       // 0..3 when tid<128
  const int chloc = tid & 31;
  const int mych  = gblk*32 + chloc;
  float c_reg = 0.f;
  if (tid < 128) c_reg = prev_c[(long)(b0 + ub)*C_ + mych];

  float winb_r = (tid < 120) ? win_b[tid % 30] : 0.f;

  // ---- preamble staging ----
  for (int i = tid; i < NB*KX; i += NTH) {
    int bb = i / KX, k = i % KX;
    int b = b0 + bb;
    float v;
    if      (k < 3)  v = x[((long)b*T_ + 0)*3 + k];
    else if (k < 4)  v = 0.f;
    else if (k < 64) v = w_old[b*V_ + (k-4)];
    else             v = prev_h[(long)b*C_ + (k-64)];
    hx[bb][k] = v;
  }
  for (int i = tid; i < NB*K_; i += NTH)
    kap_lds[i/K_][i%K_] = kappa_old[(b0 + i/K_)*K_ + i%K_];
  if (tid < NB) scale_lds[tid] = (float)U_ / text_lens[b0 + tid];
  for (int i = tid; i < NB*U_; i += NTH) {          // one-hot -> char id
    int bb = i / U_, u = i % U_;
    const float* oh = onehots + ((long)(b0+bb)*U_ + u)*V_;
    int best = 0; float bv = oh[0];
    for (int vv = 1; vv < V_; ++vv) { float q = oh[vv]; if (q > bv) { bv = q; best = vv; } }
    ids_lds[bb][u] = best;
  }
  __syncthreads();

  for (int t = 0; t < T_; ++t) {
    // ---- A: gates GEMM (k x colhalf split across 16 waves; 1 col/lane, f16 wts) ----
    float acc[NB];
    #pragma unroll
    for (int bb = 0; bb < NB; ++bb) acc[bb] = (kq == 0) ? bias1 : 0.f;
    #pragma unroll
    for (int bb = 0; bb < NB; ++bb) {
      const float* hxb = &hx[bb][kq*KSL];
      float a = acc[bb];
      #pragma unroll
      for (int i4 = 0; i4 < KSL/4; ++i4) {
        float4 h4 = *(const float4*)(hxb + i4*4);
        a = fmaf(__low2float (Wh2[2*i4  ]), h4.x, a);
        a = fmaf(__high2float(Wh2[2*i4  ]), h4.y, a);
        a = fmaf(__low2float (Wh2[2*i4+1]), h4.z, a);
        a = fmaf(__high2float(Wh2[2*i4+1]), h4.w, a);
      }
      acc[bb] = a;
    }
    #pragma unroll
    for (int bb = 0; bb < NB; ++bb)
      part[kq][bb][sA][lane] = acc[bb];
    __syncthreads();   // B

    // ---- C: cell update + (h,tag) publish | zero w-slots | stage x(t+1) ----
    if (tid < 128) {
      const int sr = chloc >> 4, c4 = (chloc & 15) * 4;
      float4 s = make_float4(0.f, 0.f, 0.f, 0.f);
      #pragma unroll
      for (int q = 0; q < KQ; ++q) {
        float4 v = *(const float4*)&part[q][ub][sr][c4];
        s.x += v.x; s.y += v.y; s.z += v.z; s.w += v.w;
      }
      float ig = sigm(s.x), fg = sigm(s.y), gg = tanhx(s.z), og = sigm(s.w);
      float c = fg*c_reg + ig*gg;
      c_reg = c;
      float h = og * tanhx(c);
      int b = b0 + ub;
      ull pk = ((ull)(unsigned)(t+1) << 32) | (ull)__float_as_uint(h);
      __hip_atomic_store(&hpair[(long)(t&1)*B_*C_ + (long)b*C_ + mych], pk,
                         __ATOMIC_RELAXED, __HIP_MEMORY_SCOPE_AGENT);
      out[OUT_HS + ((long)b*T_ + t)*C_ + mych] = h;
      if (t == T_-1) {
        out[OUT_H + (long)b*C_ + mych] = h;
        out[OUT_C + (long)b*C_ + mych] = c;
      }
    } else if (tid < 368) {
      int s0 = tid - 128;                 // zero 240 w-slots
      hx[s0/60][4 + s0%60] = 0.f;
    } else if (tid < 384) {
      int i = tid - 368, bb = i >> 2, k = i & 3;
      int tn = t + 1;
      hx[bb][k] = (k < 3 && tn < T_) ? x[((long)(b0+bb)*T_ + tn)*3 + k] : 0.f;
    }
    // no sync: G gated by data-dependency poll; writes disjoint LDS

    // ---- G: poll-gather (h,tag) pairs (2/thread) -> hx h-region ----
    {
      const ull* src = hpair + (long)(t&1)*B_*C_;
      const long base = (long)b0*C_ + tid*2;
      const int want = t + 1;
      ull v0, v1;
      while (true) {
        v0 = __hip_atomic_load(&src[base+0], __ATOMIC_RELAXED, __HIP_MEMORY_SCOPE_AGENT);
        v1 = __hip_atomic_load(&src[base+1], __ATOMIC_RELAXED, __HIP_MEMORY_SCOPE_AGENT);
        if ((int)(v0 >> 32) >= want && (int)(v1 >> 32) >= want) break;
      }
      int off = tid * 2, bb = off >> 9, k = off & 511;
      *(float2*)&hx[bb][64 + k] =
          make_float2(__uint_as_float((unsigned)v0), __uint_as_float((unsigned)v1));
    }
    __syncthreads();   // H

    // ---- I: window projection partials (16 waves x 32 ch, lanes 0..59) ----
    #pragma unroll
    for (int bb = 0; bb < NB; ++bb) {
      const float* hb = &hx[bb][64 + wav*32 + wh*16];
      float a = 0.f;
      #pragma unroll
      for (int i4 = 0; i4 < 4; ++i4) {
        float4 h4 = *(const float4*)(hb + i4*4);
        a = fmaf(winreg[i4*4+0], h4.x, a);
        a = fmaf(winreg[i4*4+1], h4.y, a);
        a = fmaf(winreg[i4*4+2], h4.z, a);
        a = fmaf(winreg[i4*4+3], h4.w, a);
      }
      if (lane < 60) part[wav>>1][bb][wav&1][lane] = a;
    }
    __syncthreads();   // J

    // ---- K: reduce 32 partials -> p = exp(.+winb); update kappa ----
    if (tid < 120) {
      int bb = tid / 30, j = tid % 30;
      float s = 0.f;
      #pragma unroll
      for (int q = 0; q < KQ; ++q) {
        s += part[q][bb][0][j] + part[q][bb][0][30+j];
        s += part[q][bb][1][j] + part[q][bb][1][30+j];
      }
      float p = __expf(s + winb_r);
      p_lds[bb][j] = p;
      if (j >= 20) {
        float nk = kap_lds[bb][j-20] + p;
        kap_lds[bb][j-20] = nk;
        if (t == T_-1 && gblk == 0) out[OUT_KAP + (b0+bb)*K_ + (j-20)] = nk;
      }
    }
    __syncthreads();   // L

    // ---- M (waves 0-3): fused phi + w-scatter (wave = batch; u = lane) ----
    if (wav < NB) {
      int bb = wav, u = lane;
      float s = 0.f;
      float uf = (float)u;
      #pragma unroll
      for (int k = 0; k < K_; ++k) {
        float d = kap_lds[bb][k] - uf;
        s += p_lds[bb][k] * __expf(-p_lds[bb][10+k]*d*d);
      }
      float phiv = s * scale_lds[bb];
      atomicAdd(&hx[bb][4 + ids_lds[bb][u]], phiv);   // ds_add_f32, in-wave order
      if (t == T_-1 && gblk == 0) out[OUT_PHI + (b0+bb)*65 + u] = phiv;
    }
    if (t == T_-1 && gblk == 0 && tid < NB) {         // u = 64 tail of phi output
      int b2 = tid;
      float s2 = 0.f;
      #pragma unroll
      for (int k = 0; k < K_; ++k) {
        float d = kap_lds[b2][k] - 64.f;
        s2 += p_lds[b2][k] * __expf(-p_lds[b2][10+k]*d*d);
      }
      out[OUT_PHI + (b0+b2)*65 + 64] = s2 * scale_lds[b2];
    }
    __syncthreads();   // N: scatter complete -> w readable

    // ---- O: rotated ws-store (one WG of the group per step) ----
    if (gblk == (t & 15) && tid < 240) {
      int bb = tid / 60, v = tid % 60;
      float wv = hx[bb][4+v];
      out[OUT_WS + ((long)(b0+bb)*T_ + t)*V_ + v] = wv;
      if (t == T_-1) out[OUT_W + (b0+bb)*V_ + v] = wv;
    }
    // no sync: O and next-A only read hx; first hx write is next-C (post-B sync)
  }
}

extern "C" void kernel_launch(void* const* d_in, const int* in_sizes, int n_in,
                              void* d_out, int out_size, void* d_ws, size_t ws_size,
                              hipStream_t stream) {
  const float* x         = (const float*)d_in[0];
  const float* onehots   = (const float*)d_in[1];
  const float* text_lens = (const float*)d_in[2];
  const float* w_old     = (const float*)d_in[3];
  const float* kappa_old = (const float*)d_in[4];
  const float* prev_h    = (const float*)d_in[5];
  const float* prev_c    = (const float*)d_in[6];
  const float* W_ih      = (const float*)d_in[7];
  const float* W_hh      = (const float*)d_in[8];
  const float* b_ih      = (const float*)d_in[9];
  const float* b_hh      = (const float*)d_in[10];
  const float* win_W     = (const float*)d_in[11];
  const float* win_b     = (const float*)d_in[12];
  ull*   hpair = (ull*)d_ws;
  float* out   = (float*)d_out;

  // zero the (h,tag) pair region (stale tags from prior replay must read < 1)
  hipMemsetAsync(d_ws, 0, 2ull*B_*C_*sizeof(ull), stream);

  lstm_attn_persistent<<<NWG, NTH, 0, stream>>>(
      x, onehots, text_lens, w_old, kappa_old, prev_h, prev_c,
      W_ih, W_hh, b_ih, b_hh, win_W, win_b, hpair, out);
}

// Round 10
// 4715.031 us; speedup vs baseline: 1.3252x; 1.3252x over previous
//
#include <hip/hip_runtime.h>
#include <math.h>

#define B_  64
#define T_  800
#define U_  64
#define V_  60
#define C_  512
#define K_  10
#define KX  576   // hx row: [0..3]=x+pad, [4..63]=w, [64..575]=h
#define NWG 256
#define NTH 512
#define KQ  8     // k-split across 8 waves
#define KSL 72    // KX / KQ
#define NB  4     // batches per group
#define GRPWG 16  // WGs per group

typedef unsigned long long ull;

// ws: ull hpair[2][B][C] (h value lo32, tag hi32), agent-scope ONLY (replay-safe)
__device__ __forceinline__ float sigm(float v)  { return 1.f/(1.f+__expf(-v)); }
__device__ __forceinline__ float tanhx(float v) { return 1.f - 2.f/(__expf(2.f*v)+1.f); }

__device__ __forceinline__ ull ldp(const ull* p) {
  return __hip_atomic_load(p, __ATOMIC_RELAXED, __HIP_MEMORY_SCOPE_AGENT);
}

__global__ __launch_bounds__(NTH, 2)
void lstm_attn_persistent(
    const float* __restrict__ x,         // [B,T,3]
    const float* __restrict__ onehots,   // [B,U,V]
    const float* __restrict__ text_lens, // [B,1]
    const float* __restrict__ w_old,     // [B,V]
    const float* __restrict__ kappa_old, // [B,K]
    const float* __restrict__ prev_h,    // [B,C]
    const float* __restrict__ prev_c,    // [B,C]
    const float* __restrict__ W_ih,      // [4C, 63]
    const float* __restrict__ W_hh,      // [4C, C]
    const float* __restrict__ b_ih,      // [4C]
    const float* __restrict__ b_hh,      // [4C]
    const float* __restrict__ win_W,     // [30, C]
    const float* __restrict__ win_b,     // [30]
    ull* __restrict__ hpair,
    float* __restrict__ out)
{
  const long OUT_WS  = 0;
  const long OUT_HS  = (long)B_*T_*V_;
  const long OUT_H   = OUT_HS + (long)B_*T_*C_;
  const long OUT_C   = OUT_H  + (long)B_*C_;
  const long OUT_W   = OUT_C  + (long)B_*C_;
  const long OUT_KAP = OUT_W  + (long)B_*V_;
  const long OUT_PHI = OUT_KAP+ (long)B_*K_;

  const int tid  = threadIdx.x;
  const int kq   = tid >> 6;        // wave id = k-slice
  const int lane = tid & 63;
  const int bid  = blockIdx.x;
  const int grp  = bid & 15;        // group (4 batches)
  const int gblk = bid >> 4;        // 0..15: 128-gate-col block / 32-ch h chunk
  const int b0   = grp * NB;

  // per-wave needed h range: GEMM [kq*72-64, kq*72+8) U window [kq*64, (kq+1)*64)
  const int rlo = kq ? (kq*KSL - 64) : 0;
  const int rhi = kq*64 + 64;

  __shared__ __align__(16) float hx[NB][KX];
  __shared__ __align__(16) float part[KQ][NB][2][68];   // gate partials (padded)
  __shared__ __align__(16) float wpart[KQ][NB][68];     // window partials
  __shared__ float p_lds[NB][32];
  __shared__ float kap_lds[NB][12];
  __shared__ float scale_lds[NB];
  __shared__ float winb_lds[32];
  __shared__ int   ids_lds[NB][64];

  // ---- persistent registers: 2 gate cols per lane (r4 datapath, f32) ----
  float Wreg[2][KSL];
  float bias2[2];
  #pragma unroll
  for (int s = 0; s < 2; ++s) {
    int gp   = gblk*128 + lane + 64*s;
    int gate = gp & 3;
    int ch   = gp >> 2;
    int row  = gate*C_ + ch;
    #pragma unroll
    for (int i = 0; i < KSL; ++i) {
      int k = kq*KSL + i;
      float v;
      if      (k < 3)  v = W_ih[row*63 + k];
      else if (k == 3) v = 0.f;
      else if (k < 64) v = W_ih[row*63 + (k-1)];
      else             v = W_hh[row*C_ + (k-64)];
      Wreg[s][i] = v;
    }
    bias2[s] = b_ih[row] + b_hh[row];
  }

  // window weights: lanes 0..59 -> (wj=lane%30, wh=lane/30), own 64-ch slice
  const int wj = lane % 30;
  const int wh = (lane < 60) ? (lane / 30) : 0;
  float winreg[32];
  #pragma unroll
  for (int i = 0; i < 32; ++i)
    winreg[i] = win_W[wj*C_ + kq*64 + wh*32 + i];

  // cell state: tid<128 owns (ub = tid>>5, ch = gblk*32 + (tid&31))
  const int ub    = tid >> 5;
  const int chloc = tid & 31;
  const int mych  = gblk*32 + chloc;
  float c_reg = 0.f;
  if (tid < 128) c_reg = prev_c[(long)(b0 + ub)*C_ + mych];

  // ---- preamble ----
  for (int i = tid; i < NB*KX; i += NTH) {
    int bb = i / KX, k = i % KX;
    int b = b0 + bb;
    float v;
    if      (k < 3)  v = x[((long)b*T_ + 0)*3 + k];
    else if (k < 4)  v = 0.f;
    else if (k < 64) v = w_old[b*V_ + (k-4)];
    else             v = prev_h[(long)b*C_ + (k-64)];
    hx[bb][k] = v;
  }
  for (int i = tid; i < NB*K_; i += NTH)
    kap_lds[i/K_][i%K_] = kappa_old[(b0 + i/K_)*K_ + i%K_];
  if (tid < NB) scale_lds[tid] = (float)U_ / text_lens[b0 + tid];
  if (tid < 30) winb_lds[tid] = win_b[tid];
  for (int i = tid; i < NB*U_; i += NTH) {
    int bb = i / U_, u = i % U_;
    const float* oh = onehots + ((long)(b0+bb)*U_ + u)*V_;
    int best = 0; float bv = oh[0];
    for (int vv = 1; vv < V_; ++vv) { float q = oh[vv]; if (q > bv) { bv = q; best = vv; } }
    ids_lds[bb][u] = best;
  }
  __syncthreads();

  for (int t = 0; t < T_; ++t) {
    // ---- A: gates GEMM (k-slice kq, 2 cols/lane) ----
    float acc[NB][2];
    #pragma unroll
    for (int bb = 0; bb < NB; ++bb) {
      acc[bb][0] = (kq == 0) ? bias2[0] : 0.f;
      acc[bb][1] = (kq == 0) ? bias2[1] : 0.f;
    }
    #pragma unroll
    for (int bb = 0; bb < NB; ++bb) {
      const float* hxb = &hx[bb][kq*KSL];
      float a0 = acc[bb][0], a1 = acc[bb][1];
      #pragma unroll
      for (int i4 = 0; i4 < KSL/4; ++i4) {
        float4 h4 = *(const float4*)(hxb + i4*4);
        a0 = fmaf(Wreg[0][i4*4+0], h4.x, a0);
        a0 = fmaf(Wreg[0][i4*4+1], h4.y, a0);
        a0 = fmaf(Wreg[0][i4*4+2], h4.z, a0);
        a0 = fmaf(Wreg[0][i4*4+3], h4.w, a0);
        a1 = fmaf(Wreg[1][i4*4+0], h4.x, a1);
        a1 = fmaf(Wreg[1][i4*4+1], h4.y, a1);
        a1 = fmaf(Wreg[1][i4*4+2], h4.z, a1);
        a1 = fmaf(Wreg[1][i4*4+3], h4.w, a1);
      }
      acc[bb][0] = a0; acc[bb][1] = a1;
    }
    #pragma unroll
    for (int bb = 0; bb < NB; ++bb) {
      part[kq][bb][0][lane] = acc[bb][0];
      part[kq][bb][1][lane] = acc[bb][1];
    }
    __syncthreads();   // B: gate partials ready

    // ---- C (waves 0-1): cell update + tagged publish (agent scope) ----
    if (tid < 128) {
      const int sr = chloc >> 4, c4 = (chloc & 15) * 4;
      float4 s = make_float4(0.f, 0.f, 0.f, 0.f);
      #pragma unroll
      for (int q = 0; q < KQ; ++q) {
        float4 v = *(const float4*)&part[q][ub][sr][c4];
        s.x += v.x; s.y += v.y; s.z += v.z; s.w += v.w;
      }
      float ig = sigm(s.x), fg = sigm(s.y), gg = tanhx(s.z), og = sigm(s.w);
      float c = fg*c_reg + ig*gg;
      c_reg = c;
      float h = og * tanhx(c);
      int b = b0 + ub;
      ull pk = ((ull)(unsigned)(t+1) << 32) | (ull)__float_as_uint(h);
      __hip_atomic_store(&hpair[(long)(t&1)*B_*C_ + (long)b*C_ + mych], pk,
                         __ATOMIC_RELAXED, __HIP_MEMORY_SCOPE_AGENT);
      out[OUT_HS + ((long)b*T_ + t)*C_ + mych] = h;
      if (t == T_-1) {
        out[OUT_H + (long)b*C_ + mych] = h;
        out[OUT_C + (long)b*C_ + mych] = c;
      }
    }
    // no barrier: P is gated by the tags themselves

    // ---- P: per-wave poll+gather own range [rlo,rhi) for 4 batches ----
    {
      const ull* src = hpair + (long)(t&1)*B_*C_;
      const int want = t + 1;
      const int ch = rlo + lane*2;
      const bool act = ch < rhi;
      const ull* q0 = src + (long)(b0+0)*C_ + ch;
      const ull* q1 = src + (long)(b0+1)*C_ + ch;
      const ull* q2 = src + (long)(b0+2)*C_ + ch;
      const ull* q3 = src + (long)(b0+3)*C_ + ch;
      ull a0=0,a1=0,c0=0,c1=0,e0=0,e1=0,g0=0,g1=0;
      while (true) {
        bool ok = true;
        if (act) {
          a0 = ldp(q0); a1 = ldp(q0+1);
          c0 = ldp(q1); c1 = ldp(q1+1);
          e0 = ldp(q2); e1 = ldp(q2+1);
          g0 = ldp(q3); g1 = ldp(q3+1);
          ok = (int)(a0>>32) >= want && (int)(a1>>32) >= want &&
               (int)(c0>>32) >= want && (int)(c1>>32) >= want &&
               (int)(e0>>32) >= want && (int)(e1>>32) >= want &&
               (int)(g0>>32) >= want && (int)(g1>>32) >= want;
        }
        if (__all(ok)) break;
      }
      if (act) {
        *(float2*)&hx[0][64+ch] = make_float2(__uint_as_float((unsigned)a0),
                                              __uint_as_float((unsigned)a1));
        *(float2*)&hx[1][64+ch] = make_float2(__uint_as_float((unsigned)c0),
                                              __uint_as_float((unsigned)c1));
        *(float2*)&hx[2][64+ch] = make_float2(__uint_as_float((unsigned)e0),
                                              __uint_as_float((unsigned)e1));
        *(float2*)&hx[3][64+ch] = make_float2(__uint_as_float((unsigned)g0),
                                              __uint_as_float((unsigned)g1));
      }
    }
    // no barrier: I reads only this wave's own gathered slice

    // ---- I: window partials (own 64-ch slice) ----
    #pragma unroll
    for (int bb = 0; bb < NB; ++bb) {
      const float* hb = &hx[bb][64 + kq*64 + wh*32];
      float a = 0.f;
      #pragma unroll
      for (int i4 = 0; i4 < 8; ++i4) {
        float4 h4 = *(const float4*)(hb + i4*4);
        a = fmaf(winreg[i4*4+0], h4.x, a);
        a = fmaf(winreg[i4*4+1], h4.y, a);
        a = fmaf(winreg[i4*4+2], h4.z, a);
        a = fmaf(winreg[i4*4+3], h4.w, a);
      }
      if (lane < 60) wpart[kq][bb][lane] = a;
    }
    __syncthreads();   // J: window partials ready

    // ---- KM (waves 0-3, wave = batch bb): p/kappa, phi, w-scatter, x, O ----
    if (kq < NB) {
      const int bb = kq;
      // K: lanes 0..29 -> p; lanes 20..29 also kappa
      if (lane < 30) {
        float s = 0.f;
        #pragma unroll
        for (int q = 0; q < KQ; ++q) s += wpart[q][bb][lane] + wpart[q][bb][30+lane];
        float p = __expf(s + winb_lds[lane]);
        p_lds[bb][lane] = p;
        if (lane >= 20) {
          float nk = kap_lds[bb][lane-20] + p;
          kap_lds[bb][lane-20] = nk;
          if (t == T_-1 && gblk == 0) out[OUT_KAP + (b0+bb)*K_ + (lane-20)] = nk;
        }
      }
      // zero w-slots (own batch) + stage x(t+1)
      if (lane < 60) hx[bb][4+lane] = 0.f;
      else if (lane < 63) {
        int tn = t + 1;
        hx[bb][lane-60] = (tn < T_) ? x[((long)(b0+bb)*T_ + tn)*3 + (lane-60)] : 0.f;
      }
      // M: phi(u=lane) + scatter (same-wave LDS FIFO orders zero < add < read)
      {
        float s = 0.f;
        float uf = (float)lane;
        #pragma unroll
        for (int k = 0; k < K_; ++k) {
          float d = kap_lds[bb][k] - uf;
          s += p_lds[bb][k] * __expf(-p_lds[bb][10+k]*d*d);
        }
        float phiv = s * scale_lds[bb];
        atomicAdd(&hx[bb][4 + ids_lds[bb][lane]], phiv);
        if (t == T_-1 && gblk == 0) {
          out[OUT_PHI + (b0+bb)*65 + lane] = phiv;
          if (lane == 0) {                             // phi tail u=64
            float s2 = 0.f;
            #pragma unroll
            for (int k = 0; k < K_; ++k) {
              float d = kap_lds[bb][k] - 64.f;
              s2 += p_lds[bb][k] * __expf(-p_lds[bb][10+k]*d*d);
            }
            out[OUT_PHI + (b0+bb)*65 + 64] = s2 * scale_lds[bb];
          }
        }
      }
      // O: rotated ws-store (own batch)
      if (gblk == (t & 15) && lane < 60) {
        float wv = hx[bb][4+lane];
        out[OUT_WS + ((long)(b0+bb)*T_ + t)*V_ + lane] = wv;
        if (t == T_-1) out[OUT_W + (b0+bb)*V_ + lane] = wv;
      }
    }
    __syncthreads();   // N: w/x ready for next A (wave 0 reads all batches)
  }
}

extern "C" void kernel_launch(void* const* d_in, const int* in_sizes, int n_in,
                              void* d_out, int out_size, void* d_ws, size_t ws_size,
                              hipStream_t stream) {
  const float* x         = (const float*)d_in[0];
  const float* onehots   = (const float*)d_in[1];
  const float* text_lens = (const float*)d_in[2];
  const float* w_old     = (const float*)d_in[3];
  const float* kappa_old = (const float*)d_in[4];
  const float* prev_h    = (const float*)d_in[5];
  const float* prev_c    = (const float*)d_in[6];
  const float* W_ih      = (const float*)d_in[7];
  const float* W_hh      = (const float*)d_in[8];
  const float* b_ih      = (const float*)d_in[9];
  const float* b_hh      = (const float*)d_in[10];
  const float* win_W     = (const float*)d_in[11];
  const float* win_b     = (const float*)d_in[12];
  ull*   hpair = (ull*)d_ws;
  float* out   = (float*)d_out;

  // zero the tagged region (stale tags from prior replay must read < 1)
  hipMemsetAsync(d_ws, 0, 2ull*B_*C_*sizeof(ull), stream);

  lstm_attn_persistent<<<NWG, NTH, 0, stream>>>(
      x, onehots, text_lens, w_old, kappa_old, prev_h, prev_c,
      W_ih, W_hh, b_ih, b_hh, win_W, win_b, hpair, out);
}

// Round 11
// 4325.831 us; speedup vs baseline: 1.4445x; 1.0900x over previous
//
#include <hip/hip_runtime.h>
#include <math.h>

#define B_  64
#define T_  800
#define U_  64
#define V_  60
#define C_  512
#define K_  10
#define KXF 584   // f16 row: [0..2]=x, [3]=0, [4..63]=w, [64..575]=h, pad to 584
#define NWG 256
#define NTH 512
#define KQ  8     // k-split across 8 waves
#define KSL 72    // (64+512) / 8
#define NB  4     // batches per group
#define GRPWG 16  // WGs per group

typedef unsigned long long ull;
typedef _Float16 f16;
typedef _Float16 f16x2 __attribute__((ext_vector_type(2)));

// ws: ull hpair[2][B][C] (h f32 lo32, tag hi32), agent-scope ONLY (replay-safe)
__device__ __forceinline__ float sigm(float v)  { return 1.f/(1.f+__expf(-v)); }
__device__ __forceinline__ float tanhx(float v) { return 1.f - 2.f/(__expf(2.f*v)+1.f); }

__device__ __forceinline__ ull ldp(const ull* p) {
  return __hip_atomic_load(p, __ATOMIC_RELAXED, __HIP_MEMORY_SCOPE_AGENT);
}
__device__ __forceinline__ float dot2(f16x2 a, f16x2 b, float c) {
  return __builtin_amdgcn_fdot2(a, b, c, false);   // v_dot2_f32_f16
}
__device__ __forceinline__ f16x2 bc2(unsigned u) {
  return __builtin_bit_cast(f16x2, u);
}
__device__ __forceinline__ float wfetch(const float* __restrict__ W_ih,
                                        const float* __restrict__ W_hh,
                                        int row, int k) {
  if (k < 3)  return W_ih[row*63 + k];
  if (k == 3) return 0.f;
  if (k < 64) return W_ih[row*63 + (k-1)];
  return W_hh[row*C_ + (k-64)];
}

__global__ __launch_bounds__(NTH, 2)
void lstm_attn_persistent(
    const float* __restrict__ x,         // [B,T,3]
    const float* __restrict__ onehots,   // [B,U,V]
    const float* __restrict__ text_lens, // [B,1]
    const float* __restrict__ w_old,     // [B,V]
    const float* __restrict__ kappa_old, // [B,K]
    const float* __restrict__ prev_h,    // [B,C]
    const float* __restrict__ prev_c,    // [B,C]
    const float* __restrict__ W_ih,      // [4C, 63]
    const float* __restrict__ W_hh,      // [4C, C]
    const float* __restrict__ b_ih,      // [4C]
    const float* __restrict__ b_hh,      // [4C]
    const float* __restrict__ win_W,     // [30, C]
    const float* __restrict__ win_b,     // [30]
    ull* __restrict__ hpair,
    float* __restrict__ out)
{
  const long OUT_WS  = 0;
  const long OUT_HS  = (long)B_*T_*V_;
  const long OUT_H   = OUT_HS + (long)B_*T_*C_;
  const long OUT_C   = OUT_H  + (long)B_*C_;
  const long OUT_W   = OUT_C  + (long)B_*C_;
  const long OUT_KAP = OUT_W  + (long)B_*V_;
  const long OUT_PHI = OUT_KAP+ (long)B_*K_;

  const int tid  = threadIdx.x;
  const int kq   = tid >> 6;        // wave id = k-slice
  const int lane = tid & 63;
  const int bid  = blockIdx.x;
  const int grp  = bid & 15;        // group (4 batches)
  const int gblk = bid >> 4;        // 0..15: 128-gate-col block / 32-ch h chunk
  const int b0   = grp * NB;

  // per-wave needed h range: GEMM [kq*72-64, kq*72+8) U window [kq*64, (kq+1)*64)
  const int rlo = kq ? (kq*KSL - 64) : 0;
  const int rhi = kq*64 + 64;

  __shared__ __align__(16) f16   hxh[NB][KXF];          // f16 staged [x|w|h]
  __shared__ __align__(16) float wbuf[NB][64];          // f32 w (scatter + outputs)
  __shared__ __align__(16) float part[KQ][NB][2][68];   // gate partials f32
  __shared__ __align__(16) float wpart[KQ][NB][68];     // window partials f32
  __shared__ float p_lds[NB][32];
  __shared__ float kap_lds[NB][12];
  __shared__ float scale_lds[NB];
  __shared__ float winb_lds[32];
  __shared__ int   ids_lds[NB][64];

  // ---- persistent registers: f16 k-packed weights, 2 gate cols per lane ----
  f16x2 Wh[2][KSL/2];               // 72 VGPRs
  float bias2[2];
  #pragma unroll
  for (int s = 0; s < 2; ++s) {
    int gp   = gblk*128 + lane + 64*s;
    int gate = gp & 3;
    int ch   = gp >> 2;
    int row  = gate*C_ + ch;
    #pragma unroll
    for (int i = 0; i < KSL/2; ++i) {
      float w0 = wfetch(W_ih, W_hh, row, kq*KSL + 2*i);
      float w1 = wfetch(W_ih, W_hh, row, kq*KSL + 2*i + 1);
      f16x2 p; p[0] = (f16)w0; p[1] = (f16)w1;
      Wh[s][i] = p;
    }
    bias2[s] = b_ih[row] + b_hh[row];
  }

  // window weights f16 k-packed: lanes 0..59 -> (wj=lane%30, wh=lane/30)
  const int wj = lane % 30;
  const int wh = (lane < 60) ? (lane / 30) : 0;
  f16x2 winh[16];
  #pragma unroll
  for (int i = 0; i < 16; ++i) {
    f16x2 p;
    p[0] = (f16)win_W[wj*C_ + kq*64 + wh*32 + 2*i];
    p[1] = (f16)win_W[wj*C_ + kq*64 + wh*32 + 2*i + 1];
    winh[i] = p;
  }

  // cell state: tid<128 owns (ub = tid>>5, ch = gblk*32 + (tid&31))
  const int ub    = tid >> 5;
  const int chloc = tid & 31;
  const int mych  = gblk*32 + chloc;
  float c_reg = 0.f;
  if (tid < 128) c_reg = prev_c[(long)(b0 + ub)*C_ + mych];

  // ---- preamble ----
  for (int i = tid; i < NB*576; i += NTH) {
    int bb = i / 576, k = i % 576;
    int b = b0 + bb;
    float v;
    if      (k < 3)  v = x[((long)b*T_ + 0)*3 + k];
    else if (k < 4)  v = 0.f;
    else if (k < 64) v = w_old[b*V_ + (k-4)];
    else             v = prev_h[(long)b*C_ + (k-64)];
    hxh[bb][k] = (f16)v;
  }
  for (int i = tid; i < NB*64; i += NTH) {
    int bb = i >> 6, j = i & 63;
    wbuf[bb][j] = (j < 60) ? w_old[(b0+bb)*V_ + j] : 0.f;
  }
  for (int i = tid; i < NB*K_; i += NTH)
    kap_lds[i/K_][i%K_] = kappa_old[(b0 + i/K_)*K_ + i%K_];
  if (tid < NB) scale_lds[tid] = (float)U_ / text_lens[b0 + tid];
  if (tid < 30) winb_lds[tid] = win_b[tid];
  for (int i = tid; i < NB*U_; i += NTH) {
    int bb = i / U_, u = i % U_;
    const float* oh = onehots + ((long)(b0+bb)*U_ + u)*V_;
    int best = 0; float bv = oh[0];
    for (int vv = 1; vv < V_; ++vv) { float q = oh[vv]; if (q > bv) { bv = q; best = vv; } }
    ids_lds[bb][u] = best;
  }
  __syncthreads();

  for (int t = 0; t < T_; ++t) {
    // ---- A: gates GEMM (k-slice kq, 2 cols/lane, f16 dot2) ----
    float acc[NB][2];
    #pragma unroll
    for (int bb = 0; bb < NB; ++bb) {
      acc[bb][0] = (kq == 0) ? bias2[0] : 0.f;
      acc[bb][1] = (kq == 0) ? bias2[1] : 0.f;
    }
    #pragma unroll
    for (int bb = 0; bb < NB; ++bb) {
      const uint4* hb = (const uint4*)&hxh[bb][kq*KSL];   // 144B-aligned
      float a0 = acc[bb][0], a1 = acc[bb][1];
      #pragma unroll
      for (int j = 0; j < 9; ++j) {                        // 72 f16 = 9 x b128
        uint4 hv = hb[j];
        f16x2 h0 = bc2(hv.x), h1 = bc2(hv.y), h2 = bc2(hv.z), h3 = bc2(hv.w);
        a0 = dot2(Wh[0][4*j+0], h0, a0);  a1 = dot2(Wh[1][4*j+0], h0, a1);
        a0 = dot2(Wh[0][4*j+1], h1, a0);  a1 = dot2(Wh[1][4*j+1], h1, a1);
        a0 = dot2(Wh[0][4*j+2], h2, a0);  a1 = dot2(Wh[1][4*j+2], h2, a1);
        a0 = dot2(Wh[0][4*j+3], h3, a0);  a1 = dot2(Wh[1][4*j+3], h3, a1);
      }
      acc[bb][0] = a0; acc[bb][1] = a1;
    }
    #pragma unroll
    for (int bb = 0; bb < NB; ++bb) {
      part[kq][bb][0][lane] = acc[bb][0];
      part[kq][bb][1][lane] = acc[bb][1];
    }
    __syncthreads();   // B: gate partials ready

    // ---- C (waves 0-1): cell update + tagged publish (agent scope, f32) ----
    if (tid < 128) {
      const int sr = chloc >> 4, c4 = (chloc & 15) * 4;
      float4 s = make_float4(0.f, 0.f, 0.f, 0.f);
      #pragma unroll
      for (int q = 0; q < KQ; ++q) {
        float4 v = *(const float4*)&part[q][ub][sr][c4];
        s.x += v.x; s.y += v.y; s.z += v.z; s.w += v.w;
      }
      float ig = sigm(s.x), fg = sigm(s.y), gg = tanhx(s.z), og = sigm(s.w);
      float c = fg*c_reg + ig*gg;
      c_reg = c;
      float h = og * tanhx(c);
      int b = b0 + ub;
      ull pk = ((ull)(unsigned)(t+1) << 32) | (ull)__float_as_uint(h);
      __hip_atomic_store(&hpair[(long)(t&1)*B_*C_ + (long)b*C_ + mych], pk,
                         __ATOMIC_RELAXED, __HIP_MEMORY_SCOPE_AGENT);
      out[OUT_HS + ((long)b*T_ + t)*C_ + mych] = h;
      if (t == T_-1) {
        out[OUT_H + (long)b*C_ + mych] = h;
        out[OUT_C + (long)b*C_ + mych] = c;
      }
    }
    // no barrier: P is gated by the tags themselves

    // ---- P: per-wave poll+gather own range [rlo,rhi), cvt to f16 ----
    {
      const ull* src = hpair + (long)(t&1)*B_*C_;
      const int want = t + 1;
      const int ch = rlo + lane*2;
      const bool act = ch < rhi;
      const ull* q0 = src + (long)(b0+0)*C_ + ch;
      const ull* q1 = src + (long)(b0+1)*C_ + ch;
      const ull* q2 = src + (long)(b0+2)*C_ + ch;
      const ull* q3 = src + (long)(b0+3)*C_ + ch;
      ull a0=0,a1=0,c0=0,c1=0,e0=0,e1=0,g0=0,g1=0;
      while (true) {
        bool ok = true;
        if (act) {
          a0 = ldp(q0); a1 = ldp(q0+1);
          c0 = ldp(q1); c1 = ldp(q1+1);
          e0 = ldp(q2); e1 = ldp(q2+1);
          g0 = ldp(q3); g1 = ldp(q3+1);
          ok = (int)(a0>>32) >= want && (int)(a1>>32) >= want &&
               (int)(c0>>32) >= want && (int)(c1>>32) >= want &&
               (int)(e0>>32) >= want && (int)(e1>>32) >= want &&
               (int)(g0>>32) >= want && (int)(g1>>32) >= want;
        }
        if (__all(ok)) break;
      }
      if (act) {
        f16x2 p;
        p[0] = (f16)__uint_as_float((unsigned)a0);
        p[1] = (f16)__uint_as_float((unsigned)a1);
        *(unsigned*)&hxh[0][64+ch] = __builtin_bit_cast(unsigned, p);
        p[0] = (f16)__uint_as_float((unsigned)c0);
        p[1] = (f16)__uint_as_float((unsigned)c1);
        *(unsigned*)&hxh[1][64+ch] = __builtin_bit_cast(unsigned, p);
        p[0] = (f16)__uint_as_float((unsigned)e0);
        p[1] = (f16)__uint_as_float((unsigned)e1);
        *(unsigned*)&hxh[2][64+ch] = __builtin_bit_cast(unsigned, p);
        p[0] = (f16)__uint_as_float((unsigned)g0);
        p[1] = (f16)__uint_as_float((unsigned)g1);
        *(unsigned*)&hxh[3][64+ch] = __builtin_bit_cast(unsigned, p);
      }
    }
    // no barrier: I reads only this wave's own gathered slice

    // ---- I: window partials (own 64-ch slice, f16 dot2) ----
    #pragma unroll
    for (int bb = 0; bb < NB; ++bb) {
      const uint4* hb = (const uint4*)&hxh[bb][64 + kq*64 + wh*32];
      float a = 0.f;
      #pragma unroll
      for (int j = 0; j < 4; ++j) {                        // 32 f16 = 4 x b128
        uint4 hv = hb[j];
        a = dot2(winh[4*j+0], bc2(hv.x), a);
        a = dot2(winh[4*j+1], bc2(hv.y), a);
        a = dot2(winh[4*j+2], bc2(hv.z), a);
        a = dot2(winh[4*j+3], bc2(hv.w), a);
      }
      if (lane < 60) wpart[kq][bb][lane] = a;
    }
    __syncthreads();   // J: window partials ready

    // ---- KM (waves 0-3, wave = batch bb): p/kappa, phi, w-scatter, x, O ----
    if (kq < NB) {
      const int bb = kq;
      if (lane < 30) {
        float s = 0.f;
        #pragma unroll
        for (int q = 0; q < KQ; ++q) s += wpart[q][bb][lane] + wpart[q][bb][30+lane];
        float p = __expf(s + winb_lds[lane]);
        p_lds[bb][lane] = p;
        if (lane >= 20) {
          float nk = kap_lds[bb][lane-20] + p;
          kap_lds[bb][lane-20] = nk;
          if (t == T_-1 && gblk == 0) out[OUT_KAP + (b0+bb)*K_ + (lane-20)] = nk;
        }
      }
      // zero w-slots (in-wave order: before adds) + stage x(t+1) f16
      if (lane < 60) wbuf[bb][lane] = 0.f;
      else if (lane < 63) {
        int tn = t + 1;
        hxh[bb][lane-60] = (f16)((tn < T_) ? x[((long)(b0+bb)*T_ + tn)*3 + (lane-60)] : 0.f);
      }
      // M: phi(u=lane) + f32 scatter
      {
        float s = 0.f;
        float uf = (float)lane;
        #pragma unroll
        for (int k = 0; k < K_; ++k) {
          float d = kap_lds[bb][k] - uf;
          s += p_lds[bb][k] * __expf(-p_lds[bb][10+k]*d*d);
        }
        float phiv = s * scale_lds[bb];
        atomicAdd(&wbuf[bb][ids_lds[bb][lane]], phiv);
        if (t == T_-1 && gblk == 0) {
          out[OUT_PHI + (b0+bb)*65 + lane] = phiv;
          if (lane == 0) {                             // phi tail u=64
            float s2 = 0.f;
            #pragma unroll
            for (int k = 0; k < K_; ++k) {
              float d = kap_lds[bb][k] - 64.f;
              s2 += p_lds[bb][k] * __expf(-p_lds[bb][10+k]*d*d);
            }
            out[OUT_PHI + (b0+bb)*65 + 64] = s2 * scale_lds[bb];
          }
        }
      }
      // f16 copy of w for next A (same-wave LDS FIFO: zero < add < read)
      if (lane < 60) {
        float wv = wbuf[bb][lane];
        hxh[bb][4+lane] = (f16)wv;
        // O: rotated ws-store (own batch)
        if (gblk == (t & 15)) {
          out[OUT_WS + ((long)(b0+bb)*T_ + t)*V_ + lane] = wv;
          if (t == T_-1) out[OUT_W + (b0+bb)*V_ + lane] = wv;
        }
      }
    }
    __syncthreads();   // N: w/x ready for next A (wave 0 reads all batches)
  }
}

extern "C" void kernel_launch(void* const* d_in, const int* in_sizes, int n_in,
                              void* d_out, int out_size, void* d_ws, size_t ws_size,
                              hipStream_t stream) {
  const float* x         = (const float*)d_in[0];
  const float* onehots   = (const float*)d_in[1];
  const float* text_lens = (const float*)d_in[2];
  const float* w_old     = (const float*)d_in[3];
  const float* kappa_old = (const float*)d_in[4];
  const float* prev_h    = (const float*)d_in[5];
  const float* prev_c    = (const float*)d_in[6];
  const float* W_ih      = (const float*)d_in[7];
  const float* W_hh      = (const float*)d_in[8];
  const float* b_ih      = (const float*)d_in[9];
  const float* b_hh      = (const float*)d_in[10];
  const float* win_W     = (const float*)d_in[11];
  const float* win_b     = (const float*)d_in[12];
  ull*   hpair = (ull*)d_ws;
  float* out   = (float*)d_out;

  // zero the tagged region (stale tags from prior replay must read < 1)
  hipMemsetAsync(d_ws, 0, 2ull*B_*C_*sizeof(ull), stream);

  lstm_attn_persistent<<<NWG, NTH, 0, stream>>>(
      x, onehots, text_lens, w_old, kappa_old, prev_h, prev_c,
      W_ih, W_hh, b_ih, b_hh, win_W, win_b, hpair, out);
}

// Round 12
// 4115.825 us; speedup vs baseline: 1.5182x; 1.0510x over previous
//
#include <hip/hip_runtime.h>
#include <math.h>

#define B_  64
#define T_  800
#define U_  64
#define V_  60
#define C_  512
#define K_  10
#define KXF 584   // f16 row: [0..2]=x, [3]=0, [4..63]=w, [64..575]=h, pad to 584
#define NWG 256
#define NTH 512
#define KQ  8     // k-split across 8 waves
#define KSL 72    // (64+512) / 8
#define NB  4     // batches per group
#define GRPWG 16  // WGs per group; bid%8 const per group -> one XCD (round-robin)

typedef unsigned long long ull;
typedef _Float16 f16;
typedef _Float16 f16x2 __attribute__((ext_vector_type(2)));

// ws (ull units): hl[2][B][C] local-L2 tagged pairs; hg[2][B][C] MALL tagged pairs
#define HL_N (2*B_*C_)

__device__ __forceinline__ float sigm(float v)  { return 1.f/(1.f+__expf(-v)); }
__device__ __forceinline__ float tanhx(float v) { return 1.f - 2.f/(__expf(2.f*v)+1.f); }

__device__ __forceinline__ float dot2(f16x2 a, f16x2 b, float c) {
  return __builtin_amdgcn_fdot2(a, b, c, false);   // v_dot2_f32_f16
}
__device__ __forceinline__ f16x2 bc2(unsigned u) {
  return __builtin_bit_cast(f16x2, u);
}
__device__ __forceinline__ float wfetch(const float* __restrict__ W_ih,
                                        const float* __restrict__ W_hh,
                                        int row, int k) {
  if (k < 3)  return W_ih[row*63 + k];
  if (k == 3) return 0.f;
  if (k < 64) return W_ih[row*63 + (k-1)];
  return W_hh[row*C_ + (k-64)];
}

// 4 x 16B loads, one vmcnt wait. sc0 = L1-bypass (L2-served, pollable).
__device__ __forceinline__ void ld4x16_loc(const ull* p0, const ull* p1,
                                           const ull* p2, const ull* p3,
                                           ulonglong2& r0, ulonglong2& r1,
                                           ulonglong2& r2, ulonglong2& r3) {
  asm volatile(
    "global_load_dwordx4 %0, %4, off sc0\n\t"
    "global_load_dwordx4 %1, %5, off sc0\n\t"
    "global_load_dwordx4 %2, %6, off sc0\n\t"
    "global_load_dwordx4 %3, %7, off sc0\n\t"
    "s_waitcnt vmcnt(0)"
    : "=&v"(r0), "=&v"(r1), "=&v"(r2), "=&v"(r3)
    : "v"(p0), "v"(p1), "v"(p2), "v"(p3) : "memory");
}
// same, sc0 sc1 = device-coherent (MALL) path
__device__ __forceinline__ void ld4x16_mal(const ull* p0, const ull* p1,
                                           const ull* p2, const ull* p3,
                                           ulonglong2& r0, ulonglong2& r1,
                                           ulonglong2& r2, ulonglong2& r3) {
  asm volatile(
    "global_load_dwordx4 %0, %4, off sc0 sc1\n\t"
    "global_load_dwordx4 %1, %5, off sc0 sc1\n\t"
    "global_load_dwordx4 %2, %6, off sc0 sc1\n\t"
    "global_load_dwordx4 %3, %7, off sc0 sc1\n\t"
    "s_waitcnt vmcnt(0)"
    : "=&v"(r0), "=&v"(r1), "=&v"(r2), "=&v"(r3)
    : "v"(p0), "v"(p1), "v"(p2), "v"(p3) : "memory");
}

__global__ __launch_bounds__(NTH, 2)
void lstm_attn_persistent(
    const float* __restrict__ x,         // [B,T,3]
    const float* __restrict__ onehots,   // [B,U,V]
    const float* __restrict__ text_lens, // [B,1]
    const float* __restrict__ w_old,     // [B,V]
    const float* __restrict__ kappa_old, // [B,K]
    const float* __restrict__ prev_h,    // [B,C]
    const float* __restrict__ prev_c,    // [B,C]
    const float* __restrict__ W_ih,      // [4C, 63]
    const float* __restrict__ W_hh,      // [4C, C]
    const float* __restrict__ b_ih,      // [4C]
    const float* __restrict__ b_hh,      // [4C]
    const float* __restrict__ win_W,     // [30, C]
    const float* __restrict__ win_b,     // [30]
    ull* __restrict__ hl,
    float* __restrict__ out)
{
  // start-of-kernel agent-acquire: invalidate clean stale L1/L2 lines left by
  // the previous graph replay (memset only refreshed MALL/HBM). Once per launch.
  __builtin_amdgcn_fence(__ATOMIC_ACQUIRE, "agent");

  const long OUT_WS  = 0;
  const long OUT_HS  = (long)B_*T_*V_;
  const long OUT_H   = OUT_HS + (long)B_*T_*C_;
  const long OUT_C   = OUT_H  + (long)B_*C_;
  const long OUT_W   = OUT_C  + (long)B_*C_;
  const long OUT_KAP = OUT_W  + (long)B_*V_;
  const long OUT_PHI = OUT_KAP+ (long)B_*K_;

  ull* hg = hl + HL_N;

  const int tid  = threadIdx.x;
  const int kq   = tid >> 6;        // wave id = k-slice
  const int lane = tid & 63;
  const int bid  = blockIdx.x;
  const int grp  = bid & 15;        // group (4 batches); bid%8 const -> one XCD
  const int gblk = bid >> 4;        // 0..15: 128-gate-col block / 32-ch h chunk
  const int b0   = grp * NB;

  // per-wave needed h range: GEMM [kq*72-64, kq*72+8) U window [kq*64, (kq+1)*64)
  const int rlo = kq ? (kq*KSL - 64) : 0;
  const int rhi = kq*64 + 64;

  __shared__ __align__(16) f16   hxh[NB][KXF];          // f16 staged [x|w|h]
  __shared__ __align__(16) float wbuf[NB][64];          // f32 w (scatter + outputs)
  __shared__ __align__(16) float part[KQ][NB][2][68];   // gate partials f32
  __shared__ __align__(16) float wpart[KQ][NB][68];     // window partials f32
  __shared__ float p_lds[NB][32];
  __shared__ float kap_lds[NB][12];
  __shared__ float scale_lds[NB];
  __shared__ float winb_lds[32];
  __shared__ int   ids_lds[NB][64];

  // ---- persistent registers: f16 k-packed weights, 2 gate cols per lane ----
  f16x2 Wh[2][KSL/2];               // 72 VGPRs
  float bias2[2];
  #pragma unroll
  for (int s = 0; s < 2; ++s) {
    int gp   = gblk*128 + lane + 64*s;
    int gate = gp & 3;
    int ch   = gp >> 2;
    int row  = gate*C_ + ch;
    #pragma unroll
    for (int i = 0; i < KSL/2; ++i) {
      float w0 = wfetch(W_ih, W_hh, row, kq*KSL + 2*i);
      float w1 = wfetch(W_ih, W_hh, row, kq*KSL + 2*i + 1);
      f16x2 p; p[0] = (f16)w0; p[1] = (f16)w1;
      Wh[s][i] = p;
    }
    bias2[s] = b_ih[row] + b_hh[row];
  }

  // window weights f16 k-packed: lanes 0..59 -> (wj=lane%30, wh=lane/30)
  const int wj = lane % 30;
  const int wh = (lane < 60) ? (lane / 30) : 0;
  f16x2 winh[16];
  #pragma unroll
  for (int i = 0; i < 16; ++i) {
    f16x2 p;
    p[0] = (f16)win_W[wj*C_ + kq*64 + wh*32 + 2*i];
    p[1] = (f16)win_W[wj*C_ + kq*64 + wh*32 + 2*i + 1];
    winh[i] = p;
  }

  // cell state: tid<128 owns (ub = tid>>5, ch = gblk*32 + (tid&31))
  const int ub    = tid >> 5;
  const int chloc = tid & 31;
  const int mych  = gblk*32 + chloc;
  float c_reg = 0.f;
  if (tid < 128) c_reg = prev_c[(long)(b0 + ub)*C_ + mych];

  // ---- preamble ----
  for (int i = tid; i < NB*576; i += NTH) {
    int bb = i / 576, k = i % 576;
    int b = b0 + bb;
    float v;
    if      (k < 3)  v = x[((long)b*T_ + 0)*3 + k];
    else if (k < 4)  v = 0.f;
    else if (k < 64) v = w_old[b*V_ + (k-4)];
    else             v = prev_h[(long)b*C_ + (k-64)];
    hxh[bb][k] = (f16)v;
  }
  for (int i = tid; i < NB*64; i += NTH) {
    int bb = i >> 6, j = i & 63;
    wbuf[bb][j] = (j < 60) ? w_old[(b0+bb)*V_ + j] : 0.f;
  }
  for (int i = tid; i < NB*K_; i += NTH)
    kap_lds[i/K_][i%K_] = kappa_old[(b0 + i/K_)*K_ + i%K_];
  if (tid < NB) scale_lds[tid] = (float)U_ / text_lens[b0 + tid];
  if (tid < 30) winb_lds[tid] = win_b[tid];
  for (int i = tid; i < NB*U_; i += NTH) {
    int bb = i / U_, u = i % U_;
    const float* oh = onehots + ((long)(b0+bb)*U_ + u)*V_;
    int best = 0; float bv = oh[0];
    for (int vv = 1; vv < V_; ++vv) { float q = oh[vv]; if (q > bv) { bv = q; best = vv; } }
    ids_lds[bb][u] = best;
  }
  __syncthreads();

  bool use_mall = false;            // wave-uniform permanent fallback

  for (int t = 0; t < T_; ++t) {
    // ---- A: gates GEMM (k-slice kq, 2 cols/lane, f16 dot2) ----
    float acc[NB][2];
    #pragma unroll
    for (int bb = 0; bb < NB; ++bb) {
      acc[bb][0] = (kq == 0) ? bias2[0] : 0.f;
      acc[bb][1] = (kq == 0) ? bias2[1] : 0.f;
    }
    #pragma unroll
    for (int bb = 0; bb < NB; ++bb) {
      const uint4* hb = (const uint4*)&hxh[bb][kq*KSL];   // 144B-aligned
      float a0 = acc[bb][0], a1 = acc[bb][1];
      #pragma unroll
      for (int j = 0; j < 9; ++j) {                        // 72 f16 = 9 x b128
        uint4 hv = hb[j];
        f16x2 h0 = bc2(hv.x), h1 = bc2(hv.y), h2 = bc2(hv.z), h3 = bc2(hv.w);
        a0 = dot2(Wh[0][4*j+0], h0, a0);  a1 = dot2(Wh[1][4*j+0], h0, a1);
        a0 = dot2(Wh[0][4*j+1], h1, a0);  a1 = dot2(Wh[1][4*j+1], h1, a1);
        a0 = dot2(Wh[0][4*j+2], h2, a0);  a1 = dot2(Wh[1][4*j+2], h2, a1);
        a0 = dot2(Wh[0][4*j+3], h3, a0);  a1 = dot2(Wh[1][4*j+3], h3, a1);
      }
      acc[bb][0] = a0; acc[bb][1] = a1;
    }
    #pragma unroll
    for (int bb = 0; bb < NB; ++bb) {
      part[kq][bb][0][lane] = acc[bb][0];
      part[kq][bb][1][lane] = acc[bb][1];
    }
    __syncthreads();   // B: gate partials ready

    // ---- C (waves 0-1): cell update + dual tagged publish ----
    if (tid < 128) {
      const int sr = chloc >> 4, c4 = (chloc & 15) * 4;
      float4 s = make_float4(0.f, 0.f, 0.f, 0.f);
      #pragma unroll
      for (int q = 0; q < KQ; ++q) {
        float4 v = *(const float4*)&part[q][ub][sr][c4];
        s.x += v.x; s.y += v.y; s.z += v.z; s.w += v.w;
      }
      float ig = sigm(s.x), fg = sigm(s.y), gg = tanhx(s.z), og = sigm(s.w);
      float c = fg*c_reg + ig*gg;
      c_reg = c;
      float h = og * tanhx(c);
      int b = b0 + ub;
      ull pk = ((ull)(unsigned)(t+1) << 32) | (ull)__float_as_uint(h);
      long hidx = (long)(t&1)*B_*C_ + (long)b*C_ + mych;
      hl[hidx] = pk;                                   // local-L2 copy (plain)
      __hip_atomic_store(&hg[hidx], pk,                // MALL copy (agent)
                         __ATOMIC_RELAXED, __HIP_MEMORY_SCOPE_AGENT);
      out[OUT_HS + ((long)b*T_ + t)*C_ + mych] = h;
      if (t == T_-1) {
        out[OUT_H + (long)b*C_ + mych] = h;
        out[OUT_C + (long)b*C_ + mych] = c;
      }
    }
    // no barrier: P is gated by the tags themselves

    // ---- P: per-wave poll+gather own range [rlo,rhi), cvt to f16 ----
    {
      const int want = t + 1;
      const int ch = rlo + lane*2;
      const bool act = ch < rhi;
      const long boff = (long)(t&1)*B_*C_ + ch;
      ulonglong2 r0, r1, r2, r3;
      r0.x=r0.y=r1.x=r1.y=r2.x=r2.y=r3.x=r3.y=0;
      int tries = 0;
      while (true) {
        bool ok = true;
        if (act) {
          const ull* base = use_mall ? hg : hl;
          const ull* p0 = base + boff + (long)(b0+0)*C_;
          const ull* p1 = base + boff + (long)(b0+1)*C_;
          const ull* p2 = base + boff + (long)(b0+2)*C_;
          const ull* p3 = base + boff + (long)(b0+3)*C_;
          if (use_mall) ld4x16_mal(p0,p1,p2,p3, r0,r1,r2,r3);
          else          ld4x16_loc(p0,p1,p2,p3, r0,r1,r2,r3);
          ok = (int)(r0.x>>32) >= want && (int)(r0.y>>32) >= want &&
               (int)(r1.x>>32) >= want && (int)(r1.y>>32) >= want &&
               (int)(r2.x>>32) >= want && (int)(r2.y>>32) >= want &&
               (int)(r3.x>>32) >= want && (int)(r3.y>>32) >= want;
        }
        if (__all(ok)) break;
        if (!use_mall && ++tries > 200) use_mall = true;  // mapping not local
      }
      if (act) {
        f16x2 p;
        p[0] = (f16)__uint_as_float((unsigned)r0.x);
        p[1] = (f16)__uint_as_float((unsigned)r0.y);
        *(unsigned*)&hxh[0][64+ch] = __builtin_bit_cast(unsigned, p);
        p[0] = (f16)__uint_as_float((unsigned)r1.x);
        p[1] = (f16)__uint_as_float((unsigned)r1.y);
        *(unsigned*)&hxh[1][64+ch] = __builtin_bit_cast(unsigned, p);
        p[0] = (f16)__uint_as_float((unsigned)r2.x);
        p[1] = (f16)__uint_as_float((unsigned)r2.y);
        *(unsigned*)&hxh[2][64+ch] = __builtin_bit_cast(unsigned, p);
        p[0] = (f16)__uint_as_float((unsigned)r3.x);
        p[1] = (f16)__uint_as_float((unsigned)r3.y);
        *(unsigned*)&hxh[3][64+ch] = __builtin_bit_cast(unsigned, p);
      }
    }
    // no barrier: I reads only this wave's own gathered slice

    // ---- I: window partials (own 64-ch slice, f16 dot2) ----
    #pragma unroll
    for (int bb = 0; bb < NB; ++bb) {
      const uint4* hb = (const uint4*)&hxh[bb][64 + kq*64 + wh*32];
      float a = 0.f;
      #pragma unroll
      for (int j = 0; j < 4; ++j) {                        // 32 f16 = 4 x b128
        uint4 hv = hb[j];
        a = dot2(winh[4*j+0], bc2(hv.x), a);
        a = dot2(winh[4*j+1], bc2(hv.y), a);
        a = dot2(winh[4*j+2], bc2(hv.z), a);
        a = dot2(winh[4*j+3], bc2(hv.w), a);
      }
      if (lane < 60) wpart[kq][bb][lane] = a;
    }
    __syncthreads();   // J: window partials ready

    // ---- KM (waves 0-3, wave = batch bb): p/kappa, phi, w-scatter, x, O ----
    if (kq < NB) {
      const int bb = kq;
      if (lane < 30) {
        float s = 0.f;
        #pragma unroll
        for (int q = 0; q < KQ; ++q) s += wpart[q][bb][lane] + wpart[q][bb][30+lane];
        float p = __expf(s + winb_lds[lane]);
        p_lds[bb][lane] = p;
        if (lane >= 20) {
          float nk = kap_lds[bb][lane-20] + p;
          kap_lds[bb][lane-20] = nk;
          if (t == T_-1 && gblk == 0) out[OUT_KAP + (b0+bb)*K_ + (lane-20)] = nk;
        }
      }
      // zero w-slots (in-wave order: before adds) + stage x(t+1) f16
      if (lane < 60) wbuf[bb][lane] = 0.f;
      else if (lane < 63) {
        int tn = t + 1;
        hxh[bb][lane-60] = (f16)((tn < T_) ? x[((long)(b0+bb)*T_ + tn)*3 + (lane-60)] : 0.f);
      }
      // M: phi(u=lane) + f32 scatter
      {
        float s = 0.f;
        float uf = (float)lane;
        #pragma unroll
        for (int k = 0; k < K_; ++k) {
          float d = kap_lds[bb][k] - uf;
          s += p_lds[bb][k] * __expf(-p_lds[bb][10+k]*d*d);
        }
        float phiv = s * scale_lds[bb];
        atomicAdd(&wbuf[bb][ids_lds[bb][lane]], phiv);
        if (t == T_-1 && gblk == 0) {
          out[OUT_PHI + (b0+bb)*65 + lane] = phiv;
          if (lane == 0) {                             // phi tail u=64
            float s2 = 0.f;
            #pragma unroll
            for (int k = 0; k < K_; ++k) {
              float d = kap_lds[bb][k] - 64.f;
              s2 += p_lds[bb][k] * __expf(-p_lds[bb][10+k]*d*d);
            }
            out[OUT_PHI + (b0+bb)*65 + 64] = s2 * scale_lds[bb];
          }
        }
      }
      // f16 copy of w for next A (same-wave LDS FIFO: zero < add < read)
      if (lane < 60) {
        float wv = wbuf[bb][lane];
        hxh[bb][4+lane] = (f16)wv;
        // O: rotated ws-store (own batch)
        if (gblk == (t & 15)) {
          out[OUT_WS + ((long)(b0+bb)*T_ + t)*V_ + lane] = wv;
          if (t == T_-1) out[OUT_W + (b0+bb)*V_ + lane] = wv;
        }
      }
    }
    __syncthreads();   // N: w/x ready for next A (all waves read hxh[.][0..63])
  }
}

extern "C" void kernel_launch(void* const* d_in, const int* in_sizes, int n_in,
                              void* d_out, int out_size, void* d_ws, size_t ws_size,
                              hipStream_t stream) {
  const float* x         = (const float*)d_in[0];
  const float* onehots   = (const float*)d_in[1];
  const float* text_lens = (const float*)d_in[2];
  const float* w_old     = (const float*)d_in[3];
  const float* kappa_old = (const float*)d_in[4];
  const float* prev_h    = (const float*)d_in[5];
  const float* prev_c    = (const float*)d_in[6];
  const float* W_ih      = (const float*)d_in[7];
  const float* W_hh      = (const float*)d_in[8];
  const float* b_ih      = (const float*)d_in[9];
  const float* b_hh      = (const float*)d_in[10];
  const float* win_W     = (const float*)d_in[11];
  const float* win_b     = (const float*)d_in[12];
  ull*   hl  = (ull*)d_ws;
  float* out = (float*)d_out;

  // zero BOTH tagged regions (stale tags from prior replay must read < 1)
  hipMemsetAsync(d_ws, 0, 2ull*HL_N*sizeof(ull), stream);

  lstm_attn_persistent<<<NWG, NTH, 0, stream>>>(
      x, onehots, text_lens, w_old, kappa_old, prev_h, prev_c,
      W_ih, W_hh, b_ih, b_hh, win_W, win_b, hl, out);
}

// Round 13
// 4092.258 us; speedup vs baseline: 1.5269x; 1.0058x over previous
//
#include <hip/hip_runtime.h>
#include <math.h>

#define B_  64
#define T_  800
#define U_  64
#define V_  60
#define C_  512
#define K_  10
#define KXF 584   // f16 row: [0..2]=x, [3]=0, [4..63]=w, [64..575]=h, pad to 584
#define NWG 256
#define NTH 512
#define KQ  8     // k-split across 8 waves
#define KSL 72    // (64+512) / 8
#define NB  4     // batches per group
#define GRPWG 16  // WGs per group (dynamically formed, XCD-preferred)

typedef unsigned long long ull;
typedef _Float16 f16;
typedef _Float16 f16x2 __attribute__((ext_vector_type(2)));

// ws (ull units): hl[2][B][C] local-L2 tagged pairs; hg[2][B][C] MALL tagged pairs
// then ints: gcnt[16], xtab[16][16]
#define HL_N (2*B_*C_)

__device__ __forceinline__ float sigm(float v)  { return 1.f/(1.f+__expf(-v)); }
__device__ __forceinline__ float tanhx(float v) { return 1.f - 2.f/(__expf(2.f*v)+1.f); }

__device__ __forceinline__ float dot2(f16x2 a, f16x2 b, float c) {
  return __builtin_amdgcn_fdot2(a, b, c, false);   // v_dot2_f32_f16
}
__device__ __forceinline__ f16x2 bc2(unsigned u) {
  return __builtin_bit_cast(f16x2, u);
}
__device__ __forceinline__ float wfetch(const float* __restrict__ W_ih,
                                        const float* __restrict__ W_hh,
                                        int row, int k) {
  if (k < 3)  return W_ih[row*63 + k];
  if (k == 3) return 0.f;
  if (k < 64) return W_ih[row*63 + (k-1)];
  return W_hh[row*C_ + (k-64)];
}

// 4 x 16B loads, one vmcnt wait. sc0 = L1-bypass (L2-served, pollable).
__device__ __forceinline__ void ld4x16_loc(const ull* p0, const ull* p1,
                                           const ull* p2, const ull* p3,
                                           ulonglong2& r0, ulonglong2& r1,
                                           ulonglong2& r2, ulonglong2& r3) {
  asm volatile(
    "global_load_dwordx4 %0, %4, off sc0\n\t"
    "global_load_dwordx4 %1, %5, off sc0\n\t"
    "global_load_dwordx4 %2, %6, off sc0\n\t"
    "global_load_dwordx4 %3, %7, off sc0\n\t"
    "s_waitcnt vmcnt(0)"
    : "=&v"(r0), "=&v"(r1), "=&v"(r2), "=&v"(r3)
    : "v"(p0), "v"(p1), "v"(p2), "v"(p3) : "memory");
}
// same, sc0 sc1 = device-coherent (MALL) path
__device__ __forceinline__ void ld4x16_mal(const ull* p0, const ull* p1,
                                           const ull* p2, const ull* p3,
                                           ulonglong2& r0, ulonglong2& r1,
                                           ulonglong2& r2, ulonglong2& r3) {
  asm volatile(
    "global_load_dwordx4 %0, %4, off sc0 sc1\n\t"
    "global_load_dwordx4 %1, %5, off sc0 sc1\n\t"
    "global_load_dwordx4 %2, %6, off sc0 sc1\n\t"
    "global_load_dwordx4 %3, %7, off sc0 sc1\n\t"
    "s_waitcnt vmcnt(0)"
    : "=&v"(r0), "=&v"(r1), "=&v"(r2), "=&v"(r3)
    : "v"(p0), "v"(p1), "v"(p2), "v"(p3) : "memory");
}

__global__ __launch_bounds__(NTH, 2)
void lstm_attn_persistent(
    const float* __restrict__ x,         // [B,T,3]
    const float* __restrict__ onehots,   // [B,U,V]
    const float* __restrict__ text_lens, // [B,1]
    const float* __restrict__ w_old,     // [B,V]
    const float* __restrict__ kappa_old, // [B,K]
    const float* __restrict__ prev_h,    // [B,C]
    const float* __restrict__ prev_c,    // [B,C]
    const float* __restrict__ W_ih,      // [4C, 63]
    const float* __restrict__ W_hh,      // [4C, C]
    const float* __restrict__ b_ih,      // [4C]
    const float* __restrict__ b_hh,      // [4C]
    const float* __restrict__ win_W,     // [30, C]
    const float* __restrict__ win_b,     // [30]
    ull* __restrict__ hl,
    float* __restrict__ out)
{
  // start-of-kernel agent-acquire: invalidate clean stale L1/L2 lines left by
  // the previous graph replay (memset only refreshed MALL/HBM). Once per launch.
  __builtin_amdgcn_fence(__ATOMIC_ACQUIRE, "agent");

  const long OUT_WS  = 0;
  const long OUT_HS  = (long)B_*T_*V_;
  const long OUT_H   = OUT_HS + (long)B_*T_*C_;
  const long OUT_C   = OUT_H  + (long)B_*C_;
  const long OUT_W   = OUT_C  + (long)B_*C_;
  const long OUT_KAP = OUT_W  + (long)B_*V_;
  const long OUT_PHI = OUT_KAP+ (long)B_*K_;

  ull* hg   = hl + HL_N;
  int* gcnt = (int*)(hl + 2*HL_N);       // [16]
  int* xtab = gcnt + 16;                 // [16][16], 0 = unclaimed, else xcd+1

  const int tid  = threadIdx.x;
  const int kq   = tid >> 6;        // wave id = k-slice
  const int lane = tid & 63;

  __shared__ __align__(16) f16   hxh[NB][KXF];          // f16 staged [x|w|h]
  __shared__ __align__(16) float wbuf[NB][64];          // f32 w (scatter + outputs)
  __shared__ __align__(16) float part[KQ][NB][2][68];   // gate partials f32
  __shared__ __align__(16) float wpart[KQ][NB][68];     // window partials f32
  __shared__ float p_lds[NB][32];
  __shared__ float kap_lds[NB][12];
  __shared__ float scale_lds[NB];
  __shared__ float winb_lds[32];
  __shared__ int   ids_lds[NB][64];
  __shared__ int   meta[2];
  __shared__ int   cons[16];

  // ---- dynamic XCD-aware group claim ----
  if (tid == 0) {
    // HW_REG_XCC_ID: id=20, offset=0, size=32 -> getreg imm = (31<<11)|20
    unsigned xcd = __builtin_amdgcn_s_getreg(63508) & 7;
    int g = -1, s = -1;
    #pragma unroll 1
    for (int probe = 0; probe < 2 && g < 0; ++probe) {   // own XCD's groups first
      int gg = (int)xcd*2 + probe;
      int ss = atomicAdd(&gcnt[gg], 1);
      if (ss < GRPWG) { g = gg; s = ss; }
    }
    #pragma unroll 1
    for (int gg = 0; gg < 16 && g < 0; ++gg) {           // overflow: any free slot
      int ss = atomicAdd(&gcnt[gg], 1);
      if (ss < GRPWG) { g = gg; s = ss; }
    }
    meta[0] = g; meta[1] = s;
    __hip_atomic_store(&xtab[g*GRPWG + s], (int)xcd + 1,
                       __ATOMIC_RELAXED, __HIP_MEMORY_SCOPE_AGENT);
  }
  __syncthreads();
  const int grp  = meta[0];
  const int gblk = meta[1];
  const int b0   = grp * NB;
  if (tid < GRPWG) {
    int v;
    do {
      v = __hip_atomic_load(&xtab[grp*GRPWG + tid],
                            __ATOMIC_RELAXED, __HIP_MEMORY_SCOPE_AGENT);
    } while (v == 0);
    cons[tid] = v;
  }
  __syncthreads();
  bool use_mall;
  {
    int x0 = cons[0], same = 1;
    #pragma unroll
    for (int i = 1; i < GRPWG; ++i) same &= (cons[i] == x0);
    use_mall = !same;               // group not on one XCD -> MALL from the start
  }

  // per-wave needed h range: GEMM [kq*72-64, kq*72+8) U window [kq*64, (kq+1)*64)
  const int rlo = kq ? (kq*KSL - 64) : 0;
  const int rhi = kq*64 + 64;

  // ---- persistent registers: f16 k-packed weights, 2 gate cols per lane ----
  f16x2 Wh[2][KSL/2];               // 72 VGPRs
  float bias2[2];
  #pragma unroll
  for (int s = 0; s < 2; ++s) {
    int gp   = gblk*128 + lane + 64*s;
    int gate = gp & 3;
    int ch   = gp >> 2;
    int row  = gate*C_ + ch;
    #pragma unroll
    for (int i = 0; i < KSL/2; ++i) {
      float w0 = wfetch(W_ih, W_hh, row, kq*KSL + 2*i);
      float w1 = wfetch(W_ih, W_hh, row, kq*KSL + 2*i + 1);
      f16x2 p; p[0] = (f16)w0; p[1] = (f16)w1;
      Wh[s][i] = p;
    }
    bias2[s] = b_ih[row] + b_hh[row];
  }

  // window weights f16 k-packed: lanes 0..59 -> (wj=lane%30, wh=lane/30)
  const int wj = lane % 30;
  const int wh = (lane < 60) ? (lane / 30) : 0;
  f16x2 winh[16];
  #pragma unroll
  for (int i = 0; i < 16; ++i) {
    f16x2 p;
    p[0] = (f16)win_W[wj*C_ + kq*64 + wh*32 + 2*i];
    p[1] = (f16)win_W[wj*C_ + kq*64 + wh*32 + 2*i + 1];
    winh[i] = p;
  }

  // cell state: tid<128 owns (ub = tid>>5, ch = gblk*32 + (tid&31))
  const int ub    = tid >> 5;
  const int chloc = tid & 31;
  const int mych  = gblk*32 + chloc;
  float c_reg = 0.f;
  if (tid < 128) c_reg = prev_c[(long)(b0 + ub)*C_ + mych];

  // ---- preamble staging ----
  for (int i = tid; i < NB*576; i += NTH) {
    int bb = i / 576, k = i % 576;
    int b = b0 + bb;
    float v;
    if      (k < 3)  v = x[((long)b*T_ + 0)*3 + k];
    else if (k < 4)  v = 0.f;
    else if (k < 64) v = w_old[b*V_ + (k-4)];
    else             v = prev_h[(long)b*C_ + (k-64)];
    hxh[bb][k] = (f16)v;
  }
  for (int i = tid; i < NB*64; i += NTH) {
    int bb = i >> 6, j = i & 63;
    wbuf[bb][j] = (j < 60) ? w_old[(b0+bb)*V_ + j] : 0.f;
  }
  for (int i = tid; i < NB*K_; i += NTH)
    kap_lds[i/K_][i%K_] = kappa_old[(b0 + i/K_)*K_ + i%K_];
  if (tid < NB) scale_lds[tid] = (float)U_ / text_lens[b0 + tid];
  if (tid < 30) winb_lds[tid] = win_b[tid];
  for (int i = tid; i < NB*U_; i += NTH) {
    int bb = i / U_, u = i % U_;
    const float* oh = onehots + ((long)(b0+bb)*U_ + u)*V_;
    int best = 0; float bv = oh[0];
    for (int vv = 1; vv < V_; ++vv) { float q = oh[vv]; if (q > bv) { bv = q; best = vv; } }
    ids_lds[bb][u] = best;
  }
  __syncthreads();

  for (int t = 0; t < T_; ++t) {
    // ---- A: gates GEMM (k-slice kq, 2 cols/lane, f16 dot2) ----
    float acc[NB][2];
    #pragma unroll
    for (int bb = 0; bb < NB; ++bb) {
      acc[bb][0] = (kq == 0) ? bias2[0] : 0.f;
      acc[bb][1] = (kq == 0) ? bias2[1] : 0.f;
    }
    #pragma unroll
    for (int bb = 0; bb < NB; ++bb) {
      const uint4* hb = (const uint4*)&hxh[bb][kq*KSL];   // 144B-aligned
      float a0 = acc[bb][0], a1 = acc[bb][1];
      #pragma unroll
      for (int j = 0; j < 9; ++j) {                        // 72 f16 = 9 x b128
        uint4 hv = hb[j];
        f16x2 h0 = bc2(hv.x), h1 = bc2(hv.y), h2 = bc2(hv.z), h3 = bc2(hv.w);
        a0 = dot2(Wh[0][4*j+0], h0, a0);  a1 = dot2(Wh[1][4*j+0], h0, a1);
        a0 = dot2(Wh[0][4*j+1], h1, a0);  a1 = dot2(Wh[1][4*j+1], h1, a1);
        a0 = dot2(Wh[0][4*j+2], h2, a0);  a1 = dot2(Wh[1][4*j+2], h2, a1);
        a0 = dot2(Wh[0][4*j+3], h3, a0);  a1 = dot2(Wh[1][4*j+3], h3, a1);
      }
      acc[bb][0] = a0; acc[bb][1] = a1;
    }
    #pragma unroll
    for (int bb = 0; bb < NB; ++bb) {
      part[kq][bb][0][lane] = acc[bb][0];
      part[kq][bb][1][lane] = acc[bb][1];
    }
    __syncthreads();   // B: gate partials ready

    // ---- C (waves 0-1): cell update + dual tagged publish ----
    if (tid < 128) {
      const int sr = chloc >> 4, c4 = (chloc & 15) * 4;
      float4 s = make_float4(0.f, 0.f, 0.f, 0.f);
      #pragma unroll
      for (int q = 0; q < KQ; ++q) {
        float4 v = *(const float4*)&part[q][ub][sr][c4];
        s.x += v.x; s.y += v.y; s.z += v.z; s.w += v.w;
      }
      float ig = sigm(s.x), fg = sigm(s.y), gg = tanhx(s.z), og = sigm(s.w);
      float c = fg*c_reg + ig*gg;
      c_reg = c;
      float h = og * tanhx(c);
      int b = b0 + ub;
      ull pk = ((ull)(unsigned)(t+1) << 32) | (ull)__float_as_uint(h);
      long hidx = (long)(t&1)*B_*C_ + (long)b*C_ + mych;
      hl[hidx] = pk;                                   // local-L2 copy (plain)
      __hip_atomic_store(&hg[hidx], pk,                // MALL copy (agent)
                         __ATOMIC_RELAXED, __HIP_MEMORY_SCOPE_AGENT);
      out[OUT_HS + ((long)b*T_ + t)*C_ + mych] = h;
      if (t == T_-1) {
        out[OUT_H + (long)b*C_ + mych] = h;
        out[OUT_C + (long)b*C_ + mych] = c;
      }
    }
    // no barrier: P is gated by the tags themselves

    // ---- P: per-wave poll+gather own range [rlo,rhi), cvt to f16 ----
    {
      const int want = t + 1;
      const int ch = rlo + lane*2;
      const bool act = ch < rhi;
      const long boff = (long)(t&1)*B_*C_ + ch;
      ulonglong2 r0, r1, r2, r3;
      r0.x=r0.y=r1.x=r1.y=r2.x=r2.y=r3.x=r3.y=0;
      int tries = 0;
      while (true) {
        bool ok = true;
        if (act) {
          const ull* base = use_mall ? hg : hl;
          const ull* p0 = base + boff + (long)(b0+0)*C_;
          const ull* p1 = base + boff + (long)(b0+1)*C_;
          const ull* p2 = base + boff + (long)(b0+2)*C_;
          const ull* p3 = base + boff + (long)(b0+3)*C_;
          if (use_mall) ld4x16_mal(p0,p1,p2,p3, r0,r1,r2,r3);
          else          ld4x16_loc(p0,p1,p2,p3, r0,r1,r2,r3);
          ok = (int)(r0.x>>32) >= want && (int)(r0.y>>32) >= want &&
               (int)(r1.x>>32) >= want && (int)(r1.y>>32) >= want &&
               (int)(r2.x>>32) >= want && (int)(r2.y>>32) >= want &&
               (int)(r3.x>>32) >= want && (int)(r3.y>>32) >= want;
        }
        if (__all(ok)) break;
        if (!use_mall && ++tries > 200) use_mall = true;  // safety net
      }
      if (act) {
        f16x2 p;
        p[0] = (f16)__uint_as_float((unsigned)r0.x);
        p[1] = (f16)__uint_as_float((unsigned)r0.y);
        *(unsigned*)&hxh[0][64+ch] = __builtin_bit_cast(unsigned, p);
        p[0] = (f16)__uint_as_float((unsigned)r1.x);
        p[1] = (f16)__uint_as_float((unsigned)r1.y);
        *(unsigned*)&hxh[1][64+ch] = __builtin_bit_cast(unsigned, p);
        p[0] = (f16)__uint_as_float((unsigned)r2.x);
        p[1] = (f16)__uint_as_float((unsigned)r2.y);
        *(unsigned*)&hxh[2][64+ch] = __builtin_bit_cast(unsigned, p);
        p[0] = (f16)__uint_as_float((unsigned)r3.x);
        p[1] = (f16)__uint_as_float((unsigned)r3.y);
        *(unsigned*)&hxh[3][64+ch] = __builtin_bit_cast(unsigned, p);
      }
    }
    // no barrier: I reads only this wave's own gathered slice

    // ---- I: window partials (own 64-ch slice, f16 dot2) ----
    #pragma unroll
    for (int bb = 0; bb < NB; ++bb) {
      const uint4* hb = (const uint4*)&hxh[bb][64 + kq*64 + wh*32];
      float a = 0.f;
      #pragma unroll
      for (int j = 0; j < 4; ++j) {                        // 32 f16 = 4 x b128
        uint4 hv = hb[j];
        a = dot2(winh[4*j+0], bc2(hv.x), a);
        a = dot2(winh[4*j+1], bc2(hv.y), a);
        a = dot2(winh[4*j+2], bc2(hv.z), a);
        a = dot2(winh[4*j+3], bc2(hv.w), a);
      }
      if (lane < 60) wpart[kq][bb][lane] = a;
    }
    __syncthreads();   // J: window partials ready

    // ---- KM (waves 0-3, wave = batch bb): p/kappa, phi, w-scatter, x, O ----
    if (kq < NB) {
      const int bb = kq;
      if (lane < 30) {
        float s = 0.f;
        #pragma unroll
        for (int q = 0; q < KQ; ++q) s += wpart[q][bb][lane] + wpart[q][bb][30+lane];
        float p = __expf(s + winb_lds[lane]);
        p_lds[bb][lane] = p;
        if (lane >= 20) {
          float nk = kap_lds[bb][lane-20] + p;
          kap_lds[bb][lane-20] = nk;
          if (t == T_-1 && gblk == 0) out[OUT_KAP + (b0+bb)*K_ + (lane-20)] = nk;
        }
      }
      // zero w-slots (in-wave order: before adds) + stage x(t+1) f16
      if (lane < 60) wbuf[bb][lane] = 0.f;
      else if (lane < 63) {
        int tn = t + 1;
        hxh[bb][lane-60] = (f16)((tn < T_) ? x[((long)(b0+bb)*T_ + tn)*3 + (lane-60)] : 0.f);
      }
      // M: phi(u=lane) + f32 scatter
      {
        float s = 0.f;
        float uf = (float)lane;
        #pragma unroll
        for (int k = 0; k < K_; ++k) {
          float d = kap_lds[bb][k] - uf;
          s += p_lds[bb][k] * __expf(-p_lds[bb][10+k]*d*d);
        }
        float phiv = s * scale_lds[bb];
        atomicAdd(&wbuf[bb][ids_lds[bb][lane]], phiv);
        if (t == T_-1 && gblk == 0) {
          out[OUT_PHI + (b0+bb)*65 + lane] = phiv;
          if (lane == 0) {                             // phi tail u=64
            float s2 = 0.f;
            #pragma unroll
            for (int k = 0; k < K_; ++k) {
              float d = kap_lds[bb][k] - 64.f;
              s2 += p_lds[bb][k] * __expf(-p_lds[bb][10+k]*d*d);
            }
            out[OUT_PHI + (b0+bb)*65 + 64] = s2 * scale_lds[bb];
          }
        }
      }
      // f16 copy of w for next A (same-wave LDS FIFO: zero < add < read)
      if (lane < 60) {
        float wv = wbuf[bb][lane];
        hxh[bb][4+lane] = (f16)wv;
        // O: rotated ws-store (own batch)
        if (gblk == (t & 15)) {
          out[OUT_WS + ((long)(b0+bb)*T_ + t)*V_ + lane] = wv;
          if (t == T_-1) out[OUT_W + (b0+bb)*V_ + lane] = wv;
        }
      }
    }
    __syncthreads();   // N: w/x ready for next A (all waves read hxh[.][0..63])
  }
}

extern "C" void kernel_launch(void* const* d_in, const int* in_sizes, int n_in,
                              void* d_out, int out_size, void* d_ws, size_t ws_size,
                              hipStream_t stream) {
  const float* x         = (const float*)d_in[0];
  const float* onehots   = (const float*)d_in[1];
  const float* text_lens = (const float*)d_in[2];
  const float* w_old     = (const float*)d_in[3];
  const float* kappa_old = (const float*)d_in[4];
  const float* prev_h    = (const float*)d_in[5];
  const float* prev_c    = (const float*)d_in[6];
  const float* W_ih      = (const float*)d_in[7];
  const float* W_hh      = (const float*)d_in[8];
  const float* b_ih      = (const float*)d_in[9];
  const float* b_hh      = (const float*)d_in[10];
  const float* win_W     = (const float*)d_in[11];
  const float* win_b     = (const float*)d_in[12];
  ull*   hl  = (ull*)d_ws;
  float* out = (float*)d_out;

  // zero tagged regions + claim tables (stale tags/claims must read 0)
  hipMemsetAsync(d_ws, 0, 2ull*HL_N*sizeof(ull) + 4096, stream);

  lstm_attn_persistent<<<NWG, NTH, 0, stream>>>(
      x, onehots, text_lens, w_old, kappa_old, prev_h, prev_c,
      W_ih, W_hh, b_ih, b_hh, win_W, win_b, hl, out);
}